// Round 3
// baseline (2953.244 us; speedup 1.0000x reference)
//
#include <hip/hip_runtime.h>
#include <hip/hip_bf16.h>
#include <cstdint>

// H=8, T=2048, E=512. Inputs/outputs are FLOAT32 (per the reference); bf16
// intermediates in workspace. All GEMMs NT: C[m][n] = sum_k A[m][k]*B[n][k].
// Per-head host loop:
//   qh = x Wq[h]^T + bq[h]      [T][E]   bf16
//   kh = y Wk[h]^T + bk[h]      [T][E]   bf16
//   vTh[f][t] = Wv[h] z^T + bv  [E][T]   bf16
//   att = softmax(qh kh^T / sqrt(T))   [T][T]  bf16
//   hoT[f][h*T+s] = sum_t vTh[f][t] att[s][t]   (hoT: [E][H*T]) bf16
// then fin[t][e] = Wf[t][:] . hoT[e][:] + bf[t] (f32); out = LN(fin + z) f32.
// Workspace peak: qh 2M | kh 2M | vTh 2M | att 8M | hoT 16M | fin 4M = 34 MB.

#define HH 8
#define TT 2048
#define EE 512
#define HT (HH * TT)

typedef __hip_bfloat16 bf16;

__device__ __forceinline__ float b2f(bf16 v) { return __bfloat162float(v); }
__device__ __forceinline__ bf16 f2b(float v) { return __float2bfloat16(v); }

template <typename CT> __device__ __forceinline__ CT cvt_out(float v);
template <> __device__ __forceinline__ float cvt_out<float>(float v) { return v; }
template <> __device__ __forceinline__ bf16 cvt_out<bf16>(float v) { return f2b(v); }

// Load 8 consecutive K-elements as f32 (16B-aligned for bf16, 32B for f32).
__device__ __forceinline__ void load8(const float* p, float* d) {
  float4 a = ((const float4*)p)[0];
  float4 b = ((const float4*)p)[1];
  d[0] = a.x; d[1] = a.y; d[2] = a.z; d[3] = a.w;
  d[4] = b.x; d[5] = b.y; d[6] = b.z; d[7] = b.w;
}
__device__ __forceinline__ void load8(const bf16* p, float* d) {
  uint4 u = *(const uint4*)p;
  const bf16* e = (const bf16*)&u;
#pragma unroll
  for (int j = 0; j < 8; j++) d[j] = b2f(e[j]);
}

// NT GEMM, 64x64 tile. M = gridDim.x*64, N = gridDim.y*64.
// A: [M x K] row-major, B: [N x K] row-major (K multiple of 32).
// C[m][n] = sum_k A[m][k]*B[n][k] + bias_m[m] + bias_n[n] (null = 0).
template <typename AT, typename BT, typename CT>
__global__ __launch_bounds__(256) void gemm_nt(
    const AT* __restrict__ A, const BT* __restrict__ B, CT* __restrict__ C,
    const float* __restrict__ bias_m, const float* __restrict__ bias_n,
    int K, int ldc) {
  const int m0 = blockIdx.x * 64;
  const int n0 = blockIdx.y * 64;

  // k-major LDS so compute phase reads contiguous float4 fragments
  __shared__ float As[32][64];
  __shared__ float Bs[32][64];

  const int tid = threadIdx.x;
  const int tx = tid & 15;        // n sub-tile
  const int ty = tid >> 4;        // m sub-tile
  const int lm = tid >> 2;        // staging: row within 64-row tile
  const int lk = (tid & 3) * 8;   // staging: k0 within 32-wide K tile

  float acc[4][4] = {{0.f}};

  for (int kt = 0; kt < K; kt += 32) {
    float a8[8], b8[8];
    load8(A + (int64_t)(m0 + lm) * K + kt + lk, a8);
    load8(B + (int64_t)(n0 + lm) * K + kt + lk, b8);
    __syncthreads();  // previous compute done before overwriting LDS
#pragma unroll
    for (int j = 0; j < 8; j++) {
      As[lk + j][lm] = a8[j];
      Bs[lk + j][lm] = b8[j];
    }
    __syncthreads();
#pragma unroll
    for (int kk = 0; kk < 32; kk++) {
      float4 a4 = *(const float4*)&As[kk][ty * 4];
      float4 b4 = *(const float4*)&Bs[kk][tx * 4];
      const float* aa = (const float*)&a4;
      const float* bb = (const float*)&b4;
#pragma unroll
      for (int i = 0; i < 4; i++)
#pragma unroll
        for (int j = 0; j < 4; j++) acc[i][j] += aa[i] * bb[j];
    }
  }

#pragma unroll
  for (int i = 0; i < 4; i++) {
    const int m = m0 + ty * 4 + i;
    const float bm = bias_m ? bias_m[m] : 0.0f;
#pragma unroll
    for (int j = 0; j < 4; j++) {
      const int n = n0 + tx * 4 + j;
      const float bn = bias_n ? bias_n[n] : 0.0f;
      C[(int64_t)m * ldc + n] = cvt_out<CT>(acc[i][j] + bm + bn);
    }
  }
}

// In-place row softmax over bf16 rows of length T, with 1/sqrt(T) pre-scale.
__global__ __launch_bounds__(256) void softmax_rows(bf16* __restrict__ S) {
  const float scale = 0.022097086912079608f;  // 1/sqrt(2048)
  bf16* p = S + (int64_t)blockIdx.x * TT;
  const int tid = threadIdx.x;
  float v[8];
  float mx = -1e30f;
#pragma unroll
  for (int i = 0; i < 8; i++) {
    v[i] = b2f(p[tid + i * 256]) * scale;
    mx = fmaxf(mx, v[i]);
  }
#pragma unroll
  for (int o = 32; o > 0; o >>= 1) mx = fmaxf(mx, __shfl_xor(mx, o));
  __shared__ float redm[4];
  __shared__ float reds[4];
  if ((tid & 63) == 0) redm[tid >> 6] = mx;
  __syncthreads();
  mx = fmaxf(fmaxf(redm[0], redm[1]), fmaxf(redm[2], redm[3]));
  float sum = 0.f;
#pragma unroll
  for (int i = 0; i < 8; i++) {
    v[i] = __expf(v[i] - mx);
    sum += v[i];
  }
#pragma unroll
  for (int o = 32; o > 0; o >>= 1) sum += __shfl_xor(sum, o);
  if ((tid & 63) == 0) reds[tid >> 6] = sum;
  __syncthreads();
  sum = reds[0] + reds[1] + reds[2] + reds[3];
  const float inv = 1.0f / sum;
#pragma unroll
  for (int i = 0; i < 8; i++) p[tid + i * 256] = f2b(v[i] * inv);
}

// out[t][:] = LayerNorm(fin[t][:] + z[t][:]) with eps=1e-4 on population var
__global__ __launch_bounds__(256) void ln_res(const float* __restrict__ F,
                                              const float* __restrict__ Z,
                                              float* __restrict__ O) {
  const int row = blockIdx.x;
  const float* f = F + (int64_t)row * EE;
  const float* z = Z + (int64_t)row * EE;
  float* o = O + (int64_t)row * EE;
  const int tid = threadIdx.x;
  const float a = f[tid] + z[tid];
  const float b = f[tid + 256] + z[tid + 256];
  float s = a + b, ss = a * a + b * b;
#pragma unroll
  for (int w = 32; w > 0; w >>= 1) {
    s += __shfl_xor(s, w);
    ss += __shfl_xor(ss, w);
  }
  __shared__ float rs[4], rss[4];
  if ((tid & 63) == 0) {
    rs[tid >> 6] = s;
    rss[tid >> 6] = ss;
  }
  __syncthreads();
  s = rs[0] + rs[1] + rs[2] + rs[3];
  ss = rss[0] + rss[1] + rss[2] + rss[3];
  const float mean = s * (1.0f / EE);
  const float var = ss * (1.0f / EE) - mean * mean;
  const float inv = rsqrtf(var + 1e-4f);
  o[tid] = (a - mean) * inv;
  o[tid + 256] = (b - mean) * inv;
}

extern "C" void kernel_launch(void* const* d_in, const int* in_sizes, int n_in,
                              void* d_out, int out_size, void* d_ws, size_t ws_size,
                              hipStream_t stream) {
  const float* x = (const float*)d_in[0];
  const float* y = (const float*)d_in[1];
  const float* z = (const float*)d_in[2];
  const float* Wq = (const float*)d_in[3];
  const float* bq = (const float*)d_in[4];
  const float* Wk = (const float*)d_in[5];
  const float* bk = (const float*)d_in[6];
  const float* Wv = (const float*)d_in[7];
  const float* bv = (const float*)d_in[8];
  const float* Wf = (const float*)d_in[9];
  const float* bfb = (const float*)d_in[10];
  float* out = (float*)d_out;

  // Workspace layout (bytes), peak 34 MB:
  char* ws = (char*)d_ws;
  const int64_t TE = (int64_t)TT * EE * sizeof(bf16);  // 2 MiB
  bf16* qh = (bf16*)(ws);                              // [T][E]
  bf16* kh = (bf16*)(ws + TE);                         // [T][E]
  bf16* vTh = (bf16*)(ws + 2 * TE);                    // [E][T]
  bf16* att = (bf16*)(ws + 3 * TE);                    // [T][T] (8 MiB)
  bf16* hoT = (bf16*)(ws + 3 * TE + (int64_t)TT * TT * sizeof(bf16));  // [E][H*T] (16 MiB)
  float* fin = (float*)(ws + 3 * TE + (int64_t)TT * TT * sizeof(bf16) +
                        (int64_t)EE * HT * sizeof(bf16));  // [T][E] fp32 (4 MiB)

  for (int h = 0; h < HH; h++) {
    const float* Wq_h = Wq + (int64_t)h * EE * EE;
    const float* Wk_h = Wk + (int64_t)h * EE * EE;
    const float* Wv_h = Wv + (int64_t)h * EE * EE;
    const float* bq_h = bq + (int64_t)h * EE;
    const float* bk_h = bk + (int64_t)h * EE;
    const float* bv_h = bv + (int64_t)h * EE;

    // qh[s][f] = x[s][:] . Wq_h[f][:] + bq_h[f]
    gemm_nt<float, float, bf16><<<dim3(TT / 64, EE / 64), 256, 0, stream>>>(
        x, Wq_h, qh, nullptr, bq_h, EE, EE);
    gemm_nt<float, float, bf16><<<dim3(TT / 64, EE / 64), 256, 0, stream>>>(
        y, Wk_h, kh, nullptr, bk_h, EE, EE);
    // vTh[f][t] = Wv_h[f][:] . z[t][:] + bv_h[f]
    gemm_nt<float, float, bf16><<<dim3(EE / 64, TT / 64), 256, 0, stream>>>(
        Wv_h, z, vTh, bv_h, nullptr, EE, TT);
    // att[s][t] = qh[s][:] . kh[t][:]
    gemm_nt<bf16, bf16, bf16><<<dim3(TT / 64, TT / 64), 256, 0, stream>>>(
        qh, kh, att, nullptr, nullptr, EE, TT);
    softmax_rows<<<TT, 256, 0, stream>>>(att);
    // hoT[f][h*T+s] = vTh[f][:] . att[s][:]
    gemm_nt<bf16, bf16, bf16><<<dim3(EE / 64, TT / 64), 256, 0, stream>>>(
        vTh, att, hoT + (int64_t)h * TT, nullptr, nullptr, TT, HT);
  }
  // fin[t][e] = Wf[t][:] . hoT[e][:] + bf[t]
  gemm_nt<float, bf16, float><<<dim3(TT / 64, EE / 64), 256, 0, stream>>>(
      Wf, hoT, fin, bfb, nullptr, HT, EE);
  ln_res<<<TT, 256, 0, stream>>>(fin, z, out);
}

// Round 4
// 528.566 us; speedup vs baseline: 5.5873x; 5.5873x over previous
//
#include <hip/hip_runtime.h>
#include <hip/hip_bf16.h>
#include <cstdint>

// H=8, T=2048, E=512. Inputs/outputs FLOAT32; bf16 intermediates.
// All GEMMs NT: C[m][n] = sum_k A[m][k]*B[n][k]  (A:[MxK] lda, B:[NxK] ldb).
// MFMA core: 128x128 tile, 4 waves, BK=32, mfma_f32_16x16x32_bf16, 4x4 frags/wave,
// global_load_lds width-16 staging (m97 structure).
// Pipeline:
//   qb/kb/vTb <- bf16 converts of inputs
//   q[h]=x Wq[h]^T+bq ; k[h]=y Wk[h]^T+bk ; vT[h][f][t]=Wv[h] z^T+bv
//   att[h]=softmax(q k^T / sqrt(T)) ; hoT[f][h*T+s]=sum_t vT[h][f][t] att[h][s][t]
//   fin[t][e]=Wf[t][:] . hoT[e][:]  (split-K=8, f32 atomicAdd; Wf staged f32->bf16)
//   out = LN(fin + bf[t] + z)

#define HH 8
#define TT 2048
#define EE 512
#define HT (HH * TT)

typedef __bf16 bf16_t;
typedef __attribute__((ext_vector_type(8))) __bf16 bf16x8;
typedef __attribute__((ext_vector_type(4))) float f32x4;

// ---------- staging helpers (one 64-row half of a 128x32 tile) ----------
// dest LDS layout: row-major [128][32] bf16; thread tid covers (row=tid>>2, k0=(tid&3)*8)
__device__ __forceinline__ void stage_half(const bf16_t* __restrict__ g, bf16_t* l) {
  __builtin_amdgcn_global_load_lds(
      (const __attribute__((address_space(1))) unsigned int*)g,
      (__attribute__((address_space(3))) unsigned int*)l, 16, 0, 0);
}
__device__ __forceinline__ void stage_half(const float* __restrict__ g, bf16_t* l) {
  float4 u = ((const float4*)g)[0];
  float4 v = ((const float4*)g)[1];
  bf16x8 o;
  o[0] = (__bf16)u.x; o[1] = (__bf16)u.y; o[2] = (__bf16)u.z; o[3] = (__bf16)u.w;
  o[4] = (__bf16)v.x; o[5] = (__bf16)v.y; o[6] = (__bf16)v.z; o[7] = (__bf16)v.w;
  *(bf16x8*)l = o;
}

template <typename CT, bool ATOMIC>
__device__ __forceinline__ void store_c(CT* p, float v) {
  if constexpr (ATOMIC) atomicAdd((float*)p, v);
  else *p = (CT)v;
}

// ---------- MFMA NT GEMM ----------
// grid: (M/128, N/128, nz). Per-z offsets: A += z*sA, B += z*sB, C += z*sC,
// bias_m += z*sBM, bias_n += z*sBN (when non-null). K multiple of 32.
template <typename AT, typename CT, bool ATOMIC>
__global__ __launch_bounds__(256) void mfma_gemm_nt(
    const AT* __restrict__ A, const bf16_t* __restrict__ B, CT* __restrict__ C,
    const float* __restrict__ bias_m, const float* __restrict__ bias_n,
    int K, int lda, int ldb, int ldc,
    int64_t sA, int64_t sB, int64_t sC, int64_t sBM, int64_t sBN) {
  const int z = blockIdx.z;
  A += z * sA;
  B += z * sB;
  C += z * sC;
  if (bias_m) bias_m += z * sBM;
  if (bias_n) bias_n += z * sBN;

  const int m0 = blockIdx.x * 128;
  const int n0 = blockIdx.y * 128;
  const int tid = threadIdx.x;

  __shared__ bf16_t sAb[128 * 32];  // 8 KB
  __shared__ bf16_t sBb[128 * 32];  // 8 KB

  // staging pointers
  const int srow = tid >> 2;
  const int scol = (tid & 3) * 8;
  const AT* a0 = A + (int64_t)(m0 + srow) * lda + scol;
  const AT* a1 = a0 + (int64_t)64 * lda;
  const bf16_t* b0 = B + (int64_t)(n0 + srow) * ldb + scol;
  const bf16_t* b1 = b0 + (int64_t)64 * ldb;
  bf16_t* la0 = sAb + tid * 8;
  bf16_t* la1 = sAb + 2048 + tid * 8;
  bf16_t* lb0 = sBb + tid * 8;
  bf16_t* lb1 = sBb + 2048 + tid * 8;

  // wave tile
  const int wave = tid >> 6;
  const int lane = tid & 63;
  const int wm = (wave >> 1) * 64;
  const int wn = (wave & 1) * 64;
  const int fr = lane & 15;  // frag row (m for A, n for B); also output col
  const int qd = lane >> 4;  // quad; output rows qd*4..+3

  f32x4 acc[4][4];
#pragma unroll
  for (int i = 0; i < 4; i++)
#pragma unroll
    for (int j = 0; j < 4; j++) acc[i][j] = (f32x4){0.f, 0.f, 0.f, 0.f};

  for (int kt = 0; kt < K; kt += 32) {
    __syncthreads();  // previous tile's reads done
    stage_half(a0 + kt, la0);
    stage_half(a1 + kt, la1);
    stage_half(b0 + kt, lb0);
    stage_half(b1 + kt, lb1);
    __syncthreads();  // staging complete (vmcnt/lgkm drained before barrier)

    bf16x8 af[4], bf_[4];
#pragma unroll
    for (int i = 0; i < 4; i++)
      af[i] = *(const bf16x8*)&sAb[(wm + i * 16 + fr) * 32 + qd * 8];
#pragma unroll
    for (int j = 0; j < 4; j++)
      bf_[j] = *(const bf16x8*)&sBb[(wn + j * 16 + fr) * 32 + qd * 8];
#pragma unroll
    for (int i = 0; i < 4; i++)
#pragma unroll
      for (int j = 0; j < 4; j++)
        acc[i][j] = __builtin_amdgcn_mfma_f32_16x16x32_bf16(af[i], bf_[j], acc[i][j], 0, 0, 0);
  }

#pragma unroll
  for (int i = 0; i < 4; i++) {
    const int row0 = m0 + wm + i * 16 + qd * 4;
#pragma unroll
    for (int j = 0; j < 4; j++) {
      const int col = n0 + wn + j * 16 + fr;
      const float bn = bias_n ? bias_n[col] : 0.f;
#pragma unroll
      for (int r = 0; r < 4; r++) {
        const float bm = bias_m ? bias_m[row0 + r] : 0.f;
        store_c<CT, ATOMIC>(&C[(int64_t)(row0 + r) * ldc + col], acc[i][j][r] + bn + bm);
      }
    }
  }
}

// ---------- f32 -> bf16 convert (n multiple of 2048) ----------
__global__ __launch_bounds__(256) void cvt_bf16(const float* __restrict__ s,
                                                bf16_t* __restrict__ d) {
  const int64_t i = ((int64_t)blockIdx.x * 256 + threadIdx.x) * 8;
  float4 u = ((const float4*)(s + i))[0];
  float4 v = ((const float4*)(s + i))[1];
  bf16x8 o;
  o[0] = (__bf16)u.x; o[1] = (__bf16)u.y; o[2] = (__bf16)u.z; o[3] = (__bf16)u.w;
  o[4] = (__bf16)v.x; o[5] = (__bf16)v.y; o[6] = (__bf16)v.z; o[7] = (__bf16)v.w;
  *(bf16x8*)(d + i) = o;
}

// ---------- in-place row softmax (rows of length T), 1/sqrt(T) pre-scale ----------
__global__ __launch_bounds__(256) void softmax_rows(bf16_t* __restrict__ S) {
  const float scale = 0.022097086912079608f;  // 1/sqrt(2048)
  bf16_t* p = S + (int64_t)blockIdx.x * TT;
  const int tid = threadIdx.x;
  float v[8];
  float mx = -1e30f;
#pragma unroll
  for (int i = 0; i < 8; i++) {
    v[i] = (float)p[tid + i * 256] * scale;
    mx = fmaxf(mx, v[i]);
  }
#pragma unroll
  for (int o = 32; o > 0; o >>= 1) mx = fmaxf(mx, __shfl_xor(mx, o));
  __shared__ float redm[4], reds[4];
  if ((tid & 63) == 0) redm[tid >> 6] = mx;
  __syncthreads();
  mx = fmaxf(fmaxf(redm[0], redm[1]), fmaxf(redm[2], redm[3]));
  float sum = 0.f;
#pragma unroll
  for (int i = 0; i < 8; i++) {
    v[i] = __expf(v[i] - mx);
    sum += v[i];
  }
#pragma unroll
  for (int o = 32; o > 0; o >>= 1) sum += __shfl_xor(sum, o);
  if ((tid & 63) == 0) reds[tid >> 6] = sum;
  __syncthreads();
  sum = reds[0] + reds[1] + reds[2] + reds[3];
  const float inv = 1.0f / sum;
#pragma unroll
  for (int i = 0; i < 8; i++) p[tid + i * 256] = (__bf16)(v[i] * inv);
}

// ---------- out = LN(fin + bf[t] + z), eps=1e-4, population var ----------
__global__ __launch_bounds__(256) void ln_res(const float* __restrict__ F,
                                              const float* __restrict__ Z,
                                              const float* __restrict__ BF,
                                              float* __restrict__ O) {
  const int row = blockIdx.x;
  const float* f = F + (int64_t)row * EE;
  const float* z = Z + (int64_t)row * EE;
  float* o = O + (int64_t)row * EE;
  const float bft = BF[row];
  const int tid = threadIdx.x;
  const float a = f[tid] + bft + z[tid];
  const float b = f[tid + 256] + bft + z[tid + 256];
  float s = a + b, ss = a * a + b * b;
#pragma unroll
  for (int w = 32; w > 0; w >>= 1) {
    s += __shfl_xor(s, w);
    ss += __shfl_xor(ss, w);
  }
  __shared__ float rs[4], rss[4];
  if ((tid & 63) == 0) {
    rs[tid >> 6] = s;
    rss[tid >> 6] = ss;
  }
  __syncthreads();
  s = rs[0] + rs[1] + rs[2] + rs[3];
  ss = rss[0] + rss[1] + rss[2] + rss[3];
  const float mean = s * (1.0f / EE);
  const float var = ss * (1.0f / EE) - mean * mean;
  const float inv = rsqrtf(var + 1e-4f);
  o[tid] = (a - mean) * inv;
  o[tid + 256] = (b - mean) * inv;
}

extern "C" void kernel_launch(void* const* d_in, const int* in_sizes, int n_in,
                              void* d_out, int out_size, void* d_ws, size_t ws_size,
                              hipStream_t stream) {
  const float* x = (const float*)d_in[0];
  const float* y = (const float*)d_in[1];
  const float* z = (const float*)d_in[2];
  const float* Wq = (const float*)d_in[3];
  const float* bq = (const float*)d_in[4];
  const float* Wk = (const float*)d_in[5];
  const float* bk = (const float*)d_in[6];
  const float* Wv = (const float*)d_in[7];
  const float* bv = (const float*)d_in[8];
  const float* Wf = (const float*)d_in[9];
  const float* bfb = (const float*)d_in[10];
  float* out = (float*)d_out;

  const size_t MB = 1ull << 20;
  char* p = (char*)d_ws;

  // common converts
  const int64_t nTE = (int64_t)TT * EE;       // 1M
  const int64_t nW = (int64_t)HH * EE * EE;   // 2M

  if (ws_size >= 151 * MB) {
    // ---- FULL layout (head-batched), 150 MB ----
    bf16_t* xb = (bf16_t*)(p + 0 * MB);
    bf16_t* yb = (bf16_t*)(p + 2 * MB);
    bf16_t* zb = (bf16_t*)(p + 4 * MB);
    bf16_t* Wqb = (bf16_t*)(p + 6 * MB);
    bf16_t* Wkb = (bf16_t*)(p + 10 * MB);
    bf16_t* Wvb = (bf16_t*)(p + 14 * MB);
    bf16_t* q = (bf16_t*)(p + 18 * MB);    // [8][T][E]
    bf16_t* k = (bf16_t*)(p + 34 * MB);    // [8][T][E]
    bf16_t* vT = (bf16_t*)(p + 50 * MB);   // [8][E][T]
    bf16_t* att = (bf16_t*)(p + 66 * MB);  // [8][T][T]
    bf16_t* hoT = (bf16_t*)(p + 130 * MB); // [E][H*T]
    float* fin = (float*)(p + 146 * MB);   // [T][E] f32

    cvt_bf16<<<nTE / 2048, 256, 0, stream>>>(x, xb);
    cvt_bf16<<<nTE / 2048, 256, 0, stream>>>(y, yb);
    cvt_bf16<<<nTE / 2048, 256, 0, stream>>>(z, zb);
    cvt_bf16<<<nW / 2048, 256, 0, stream>>>(Wq, Wqb);
    cvt_bf16<<<nW / 2048, 256, 0, stream>>>(Wk, Wkb);
    cvt_bf16<<<nW / 2048, 256, 0, stream>>>(Wv, Wvb);

    // q[h] = x Wq[h]^T + bq[h] ; k likewise
    mfma_gemm_nt<bf16_t, bf16_t, false><<<dim3(16, 4, 8), 256, 0, stream>>>(
        xb, Wqb, q, nullptr, bq, EE, EE, EE, EE, 0, (int64_t)EE * EE, (int64_t)TT * EE, 0, EE);
    mfma_gemm_nt<bf16_t, bf16_t, false><<<dim3(16, 4, 8), 256, 0, stream>>>(
        yb, Wkb, k, nullptr, bk, EE, EE, EE, EE, 0, (int64_t)EE * EE, (int64_t)TT * EE, 0, EE);
    // vT[h][f][t] = Wv[h][f][:] . z[t][:] + bv[h][f]
    mfma_gemm_nt<bf16_t, bf16_t, false><<<dim3(4, 16, 8), 256, 0, stream>>>(
        Wvb, zb, vT, bv, nullptr, EE, EE, EE, TT, (int64_t)EE * EE, 0, (int64_t)EE * TT, EE, 0);
    // att[h][s][t] = q[h][s][:] . k[h][t][:]
    mfma_gemm_nt<bf16_t, bf16_t, false><<<dim3(16, 16, 8), 256, 0, stream>>>(
        q, k, att, nullptr, nullptr, EE, EE, EE, TT, (int64_t)TT * EE, (int64_t)TT * EE,
        (int64_t)TT * TT, 0, 0);
    softmax_rows<<<HH * TT, 256, 0, stream>>>(att);
    // hoT[f][h*T+s] = vT[h][f][:] . att[h][s][:]
    mfma_gemm_nt<bf16_t, bf16_t, false><<<dim3(4, 16, 8), 256, 0, stream>>>(
        vT, att, hoT, nullptr, nullptr, TT, TT, TT, HT, (int64_t)EE * TT, (int64_t)TT * TT,
        (int64_t)TT, 0, 0);
    // fin[t][e] = Wf[t][:] . hoT[e][:]   (split-K=8, atomic)
    hipMemsetAsync(fin, 0, (size_t)TT * EE * 4, stream);
    mfma_gemm_nt<float, float, true><<<dim3(16, 4, 8), 256, 0, stream>>>(
        Wf, hoT, fin, nullptr, nullptr, HT / 8, HT, HT, EE, HT / 8, HT / 8, 0, 0, 0);
    ln_res<<<TT, 256, 0, stream>>>(fin, z, bfb, out);
  } else {
    // ---- LEAN layout (per-head), 52 MB ----
    bf16_t* xb = (bf16_t*)(p + 0 * MB);
    bf16_t* yb = (bf16_t*)(p + 2 * MB);
    bf16_t* zb = (bf16_t*)(p + 4 * MB);
    bf16_t* Wqb = (bf16_t*)(p + 6 * MB);
    bf16_t* Wkb = (bf16_t*)(p + 10 * MB);
    bf16_t* Wvb = (bf16_t*)(p + 14 * MB);
    bf16_t* qh = (bf16_t*)(p + 18 * MB);   // [T][E]
    bf16_t* kh = (bf16_t*)(p + 20 * MB);   // [T][E]
    bf16_t* vTh = (bf16_t*)(p + 22 * MB);  // [E][T]
    bf16_t* att = (bf16_t*)(p + 24 * MB);  // [T][T]
    bf16_t* hoT = (bf16_t*)(p + 32 * MB);  // [E][H*T]
    float* fin = (float*)(p + 48 * MB);    // [T][E] f32

    cvt_bf16<<<nTE / 2048, 256, 0, stream>>>(x, xb);
    cvt_bf16<<<nTE / 2048, 256, 0, stream>>>(y, yb);
    cvt_bf16<<<nTE / 2048, 256, 0, stream>>>(z, zb);
    cvt_bf16<<<nW / 2048, 256, 0, stream>>>(Wq, Wqb);
    cvt_bf16<<<nW / 2048, 256, 0, stream>>>(Wk, Wkb);
    cvt_bf16<<<nW / 2048, 256, 0, stream>>>(Wv, Wvb);

    for (int h = 0; h < HH; h++) {
      const bf16_t* Wq_h = Wqb + (int64_t)h * EE * EE;
      const bf16_t* Wk_h = Wkb + (int64_t)h * EE * EE;
      const bf16_t* Wv_h = Wvb + (int64_t)h * EE * EE;
      mfma_gemm_nt<bf16_t, bf16_t, false><<<dim3(16, 4, 1), 256, 0, stream>>>(
          xb, Wq_h, qh, nullptr, bq + h * EE, EE, EE, EE, EE, 0, 0, 0, 0, 0);
      mfma_gemm_nt<bf16_t, bf16_t, false><<<dim3(16, 4, 1), 256, 0, stream>>>(
          yb, Wk_h, kh, nullptr, bk + h * EE, EE, EE, EE, EE, 0, 0, 0, 0, 0);
      mfma_gemm_nt<bf16_t, bf16_t, false><<<dim3(4, 16, 1), 256, 0, stream>>>(
          Wv_h, zb, vTh, bv + h * EE, nullptr, EE, EE, EE, TT, 0, 0, 0, 0, 0);
      mfma_gemm_nt<bf16_t, bf16_t, false><<<dim3(16, 16, 1), 256, 0, stream>>>(
          qh, kh, att, nullptr, nullptr, EE, EE, EE, TT, 0, 0, 0, 0, 0);
      softmax_rows<<<TT, 256, 0, stream>>>(att);
      mfma_gemm_nt<bf16_t, bf16_t, false><<<dim3(4, 16, 1), 256, 0, stream>>>(
          vTh, att, hoT + (int64_t)h * TT, nullptr, nullptr, TT, TT, TT, HT, 0, 0, 0, 0, 0);
    }
    hipMemsetAsync(fin, 0, (size_t)TT * EE * 4, stream);
    mfma_gemm_nt<float, float, true><<<dim3(16, 4, 8), 256, 0, stream>>>(
        Wf, hoT, fin, nullptr, nullptr, HT / 8, HT, HT, EE, HT / 8, HT / 8, 0, 0, 0);
    ln_res<<<TT, 256, 0, stream>>>(fin, z, bfb, out);
  }
}